// Round 1
// baseline (150.919 us; speedup 1.0000x reference)
//
#include <hip/hip_runtime.h>

#define RH 128
#define RW 128
#define CS 21    // src channels
#define CSP 24   // padded src channels (float4-aligned)
#define IH 512
#define IW 512

// ---------------- K1: antialiased bilinear downsample 512 -> 128 ----------------
// jax.image.resize(bilinear, antialias=True), scale=1/4:
// sample_f = 4*i + 1.5 ; taps j = 4i-2 .. 4i+5 ; w = max(0, 1-|sample_f-j|/4),
// normalized over in-range taps (per dimension).
__global__ void downsample_kernel(const float* __restrict__ in, float* __restrict__ out,
                                  int Cin, int Cout, int total) {
    int idx = blockIdx.x * blockDim.x + threadIdx.x;
    if (idx >= total) return;
    int c = idx % Cout;
    int t = idx / Cout;
    int x = t % RW, y = t / RW;
    if (c >= Cin) { out[idx] = 0.f; return; }  // channel padding

    float wy[8], wx[8];
    int jy[8], jx[8];
    float sy = 4.f * y + 1.5f, sx = 4.f * x + 1.5f;
    float wys = 0.f, wxs = 0.f;
#pragma unroll
    for (int k = 0; k < 8; ++k) {
        int j = 4 * y - 2 + k;
        float w = 1.f - fabsf(sy - (float)j) * 0.25f;
        if (j < 0 || j >= IH) { w = 0.f; j = 0; }
        jy[k] = j; wy[k] = w; wys += w;
        int j2 = 4 * x - 2 + k;
        float w2 = 1.f - fabsf(sx - (float)j2) * 0.25f;
        if (j2 < 0 || j2 >= IW) { w2 = 0.f; j2 = 0; }
        jx[k] = j2; wx[k] = w2; wxs += w2;
    }
    float inv = 1.f / (wys * wxs);
    float s = 0.f;
#pragma unroll
    for (int a = 0; a < 8; ++a) {
        const float* row = in + (size_t)(jy[a] * IW) * Cin + c;
        float rs = 0.f;
#pragma unroll
        for (int b = 0; b < 8; ++b) rs += wx[b] * row[jx[b] * Cin];
        s += wy[a] * rs;
    }
    out[idx] = s * inv;
}

// ---------------- K2: joint bilateral at 128x128 ----------------
// 8x8 pixel tile per block, 4 lanes per pixel (dy strided by 4), shfl reduce.
// cw = exp(-||im_p - im_c||^2/18 - ((dy-12)^2+(dx-12)^2)/128)   [w1 folded in]
// im patches: reflect padding. src patches: zero padding (skip OOR taps).
__global__ __launch_bounds__(256) void bilateral_kernel(
        const float4* __restrict__ srcp,   // [RH*RW][6] float4 (24 ch)
        const float4* __restrict__ imr,    // [RH*RW] float4 (rgb + pad)
        float* __restrict__ outr) {        // [RH*RW][21]
    int tid = threadIdx.x;
    int part = tid & 3;
    int pt = tid >> 2;                     // 0..63
    int x = blockIdx.x * 8 + (pt & 7);
    int y = blockIdx.y * 8 + (pt >> 3);

    float4 ctr = imr[y * RW + x];
    float acc[CSP];
#pragma unroll
    for (int c = 0; c < CSP; ++c) acc[c] = 0.f;

    for (int dy = part; dy < 25; dy += 4) {
        int ry = y + dy - 12;
        int ry2 = ry < 0 ? -ry : (ry > RH - 1 ? 2 * (RH - 1) - ry : ry);
        float fdy = (float)(dy - 12);
        float gy = fdy * fdy;
        bool yok = (ry >= 0) && (ry < RH);
        for (int dx = 0; dx < 25; ++dx) {
            int rx = x + dx - 12;
            int rx2 = rx < 0 ? -rx : (rx > RW - 1 ? 2 * (RW - 1) - rx : rx);
            float4 p = imr[ry2 * RW + rx2];
            float d0 = p.x - ctr.x, d1 = p.y - ctr.y, d2 = p.z - ctr.z;
            float fdx = (float)(dx - 12);
            float e = -(d0 * d0 + d1 * d1 + d2 * d2) * (1.f / 18.f)
                      - (gy + fdx * fdx) * (1.f / 128.f);
            float cw = __expf(e);
            if (yok && rx >= 0 && rx < RW) {
                const float4* sp = srcp + (size_t)(ry * RW + rx) * 6;
#pragma unroll
                for (int k = 0; k < 6; ++k) {
                    float4 s = sp[k];
                    acc[4 * k + 0] += cw * s.x;
                    acc[4 * k + 1] += cw * s.y;
                    acc[4 * k + 2] += cw * s.z;
                    acc[4 * k + 3] += cw * s.w;
                }
            }
        }
    }
    // reduce the 4 parts (lanes differ in bits 0..1)
#pragma unroll
    for (int c = 0; c < CS; ++c) {
        acc[c] += __shfl_xor(acc[c], 1);
        acc[c] += __shfl_xor(acc[c], 2);
    }
    if (part == 0) {
        float* o = outr + (size_t)(y * RW + x) * CS;
#pragma unroll
        for (int c = 0; c < CS; ++c) o[c] = acc[c];
    }
}

// ---------------- K3: bilinear upsample 128 -> 512 ----------------
// sample_f = 0.25*I - 0.375 ; 2-tap lerp; edge renormalization == index clamp.
__global__ void upsample_kernel(const float* __restrict__ inr, float* __restrict__ out, int total) {
    int idx = blockIdx.x * blockDim.x + threadIdx.x;
    if (idx >= total) return;
    int c = idx % CS;
    int t = idx / CS;
    int X = t % IW, Y = t / IW;
    float fy = 0.25f * (float)Y - 0.375f;
    float fx = 0.25f * (float)X - 0.375f;
    int y0 = (int)floorf(fy); float ty = fy - (float)y0;
    int x0 = (int)floorf(fx); float tx = fx - (float)x0;
    int y1 = y0 + 1, x1 = x0 + 1;
    y0 = min(max(y0, 0), RH - 1); y1 = min(max(y1, 0), RH - 1);
    x0 = min(max(x0, 0), RW - 1); x1 = min(max(x1, 0), RW - 1);
    float v00 = inr[(y0 * RW + x0) * CS + c], v01 = inr[(y0 * RW + x1) * CS + c];
    float v10 = inr[(y1 * RW + x0) * CS + c], v11 = inr[(y1 * RW + x1) * CS + c];
    float v0 = v00 + tx * (v01 - v00);
    float v1 = v10 + tx * (v11 - v10);
    out[idx] = v0 + ty * (v1 - v0);
}

extern "C" void kernel_launch(void* const* d_in, const int* in_sizes, int n_in,
                              void* d_out, int out_size, void* d_ws, size_t ws_size,
                              hipStream_t stream) {
    const float* src = (const float*)d_in[0];   // (1,512,512,21) f32
    const float* im  = (const float*)d_in[1];   // (1,512,512,3)  f32
    float* out = (float*)d_out;                 // (1,512,512,21) f32
    char* ws = (char*)d_ws;

    // workspace layout (total 3,211,264 B)
    float* src_r = (float*)(ws);                // [128][128][24] = 1,572,864 B
    float* im_r  = (float*)(ws + 1572864);      // [128][128][4]  =   262,144 B
    float* out_r = (float*)(ws + 1835008);      // [128][128][21] = 1,376,256 B

    int t1 = RH * RW * CSP;
    downsample_kernel<<<(t1 + 255) / 256, 256, 0, stream>>>(src, src_r, CS, CSP, t1);
    int t2 = RH * RW * 4;
    downsample_kernel<<<(t2 + 255) / 256, 256, 0, stream>>>(im, im_r, 3, 4, t2);

    dim3 g2(RW / 8, RH / 8);
    bilateral_kernel<<<g2, 256, 0, stream>>>((const float4*)src_r, (const float4*)im_r, out_r);

    int t3 = IH * IW * CS;
    upsample_kernel<<<(t3 + 255) / 256, 256, 0, stream>>>(out_r, out, t3);
}

// Round 2
// 140.248 us; speedup vs baseline: 1.0761x; 1.0761x over previous
//
#include <hip/hip_runtime.h>

#define RH 128
#define RW 128
#define CS 21    // src channels
#define CSP 24   // padded src channels (float4-aligned)
#define IH 512
#define IW 512

// ---------------- K1: antialiased bilinear downsample 512 -> 128 ----------------
__global__ void downsample_kernel(const float* __restrict__ in, float* __restrict__ out,
                                  int Cin, int Cout, int total) {
    int idx = blockIdx.x * blockDim.x + threadIdx.x;
    if (idx >= total) return;
    int c = idx % Cout;
    int t = idx / Cout;
    int x = t % RW, y = t / RW;
    if (c >= Cin) { out[idx] = 0.f; return; }  // channel padding

    float wy[8], wx[8];
    int jy[8], jx[8];
    float sy = 4.f * y + 1.5f, sx = 4.f * x + 1.5f;
    float wys = 0.f, wxs = 0.f;
#pragma unroll
    for (int k = 0; k < 8; ++k) {
        int j = 4 * y - 2 + k;
        float w = 1.f - fabsf(sy - (float)j) * 0.25f;
        if (j < 0 || j >= IH) { w = 0.f; j = 0; }
        jy[k] = j; wy[k] = w; wys += w;
        int j2 = 4 * x - 2 + k;
        float w2 = 1.f - fabsf(sx - (float)j2) * 0.25f;
        if (j2 < 0 || j2 >= IW) { w2 = 0.f; j2 = 0; }
        jx[k] = j2; wx[k] = w2; wxs += w2;
    }
    float inv = 1.f / (wys * wxs);
    float s = 0.f;
#pragma unroll
    for (int a = 0; a < 8; ++a) {
        const float* row = in + (size_t)(jy[a] * IW) * Cin + c;
        float rs = 0.f;
#pragma unroll
        for (int b = 0; b < 8; ++b) rs += wx[b] * row[jx[b] * Cin];
        s += wy[a] * rs;
    }
    out[idx] = s * inv;
}

// ---------------- K2: joint bilateral at 128x128 ----------------
// 4x4 pixel tile per block, 16 lanes per pixel (dy%4, dx%4 split), im tile in LDS.
// cw = exp(-||im_p - im_c||^2/18 - ((dy-12)^2+(dx-12)^2)/128)   [w1 folded in]
// im patches: reflect padding. src patches: zero padding (skip OOR taps).
#define TILE 4
#define REG 28            // TILE + 24
#define LPITCH 29         // padded row pitch in float4
__global__ __launch_bounds__(256) void bilateral_kernel(
        const float4* __restrict__ srcp,   // [RH*RW][6] float4 (24 ch)
        const float4* __restrict__ imr,    // [RH*RW] float4 (rgb + pad)
        float* __restrict__ outr) {        // [RH*RW][21]
    __shared__ float4 im_s[REG * LPITCH];

    int tid = threadIdx.x;
    int part = tid & 15;
    int party = part & 3;
    int partx = part >> 2;
    int pt = tid >> 4;                     // 0..15
    int px = pt & 3, py = pt >> 2;
    int x0 = blockIdx.x * TILE, y0 = blockIdx.y * TILE;
    int x = x0 + px, y = y0 + py;

    // cooperative load of im region [y0-12, y0+15] x [x0-12, x0+15], reflect
    for (int t = tid; t < REG * REG; t += 256) {
        int r = t / REG, cc = t - r * REG;
        int gy = y0 + r - 12;
        gy = gy < 0 ? -gy : (gy > RH - 1 ? 2 * (RH - 1) - gy : gy);
        int gx = x0 + cc - 12;
        gx = gx < 0 ? -gx : (gx > RW - 1 ? 2 * (RW - 1) - gx : gx);
        im_s[r * LPITCH + cc] = imr[gy * RW + gx];
    }
    __syncthreads();

    float4 ctr = im_s[(py + 12) * LPITCH + (px + 12)];
    float acc[CSP];
#pragma unroll
    for (int c = 0; c < CSP; ++c) acc[c] = 0.f;

    for (int dy = party; dy < 25; dy += 4) {
        int ry = y + dy - 12;
        float fdy = (float)(dy - 12);
        float gy = fdy * fdy;
        bool yok = (ry >= 0) && (ry < RH);
        int lrow = (py + dy) * LPITCH + px;
        for (int dx = partx; dx < 25; dx += 4) {
            float4 p = im_s[lrow + dx];
            float d0 = p.x - ctr.x, d1 = p.y - ctr.y, d2 = p.z - ctr.z;
            float fdx = (float)(dx - 12);
            float e = -(d0 * d0 + d1 * d1 + d2 * d2) * (1.f / 18.f)
                      - (gy + fdx * fdx) * (1.f / 128.f);
            float cw = __expf(e);
            int rx = x + dx - 12;
            if (yok && rx >= 0 && rx < RW) {
                const float4* sp = srcp + (size_t)(ry * RW + rx) * 6;
#pragma unroll
                for (int k = 0; k < 6; ++k) {
                    float4 s = sp[k];
                    acc[4 * k + 0] += cw * s.x;
                    acc[4 * k + 1] += cw * s.y;
                    acc[4 * k + 2] += cw * s.z;
                    acc[4 * k + 3] += cw * s.w;
                }
            }
        }
    }
    // reduce the 16 parts (lane bits 0..3)
#pragma unroll
    for (int c = 0; c < CS; ++c) {
        acc[c] += __shfl_xor(acc[c], 1);
        acc[c] += __shfl_xor(acc[c], 2);
        acc[c] += __shfl_xor(acc[c], 4);
        acc[c] += __shfl_xor(acc[c], 8);
    }
    if (part == 0) {
        float* o = outr + (size_t)(y * RW + x) * CS;
#pragma unroll
        for (int c = 0; c < CS; ++c) o[c] = acc[c];
    }
}

// ---------------- K3: bilinear upsample 128 -> 512 ----------------
__global__ void upsample_kernel(const float* __restrict__ inr, float* __restrict__ out, int total) {
    int idx = blockIdx.x * blockDim.x + threadIdx.x;
    if (idx >= total) return;
    int c = idx % CS;
    int t = idx / CS;
    int X = t % IW, Y = t / IW;
    float fy = 0.25f * (float)Y - 0.375f;
    float fx = 0.25f * (float)X - 0.375f;
    int y0 = (int)floorf(fy); float ty = fy - (float)y0;
    int x0 = (int)floorf(fx); float tx = fx - (float)x0;
    int y1 = y0 + 1, x1 = x0 + 1;
    y0 = min(max(y0, 0), RH - 1); y1 = min(max(y1, 0), RH - 1);
    x0 = min(max(x0, 0), RW - 1); x1 = min(max(x1, 0), RW - 1);
    float v00 = inr[(y0 * RW + x0) * CS + c], v01 = inr[(y0 * RW + x1) * CS + c];
    float v10 = inr[(y1 * RW + x0) * CS + c], v11 = inr[(y1 * RW + x1) * CS + c];
    float v0 = v00 + tx * (v01 - v00);
    float v1 = v10 + tx * (v11 - v10);
    out[idx] = v0 + ty * (v1 - v0);
}

extern "C" void kernel_launch(void* const* d_in, const int* in_sizes, int n_in,
                              void* d_out, int out_size, void* d_ws, size_t ws_size,
                              hipStream_t stream) {
    const float* src = (const float*)d_in[0];   // (1,512,512,21) f32
    const float* im  = (const float*)d_in[1];   // (1,512,512,3)  f32
    float* out = (float*)d_out;                 // (1,512,512,21) f32
    char* ws = (char*)d_ws;

    float* src_r = (float*)(ws);                // [128][128][24] = 1,572,864 B
    float* im_r  = (float*)(ws + 1572864);      // [128][128][4]  =   262,144 B
    float* out_r = (float*)(ws + 1835008);      // [128][128][21] = 1,376,256 B

    int t1 = RH * RW * CSP;
    downsample_kernel<<<(t1 + 255) / 256, 256, 0, stream>>>(src, src_r, CS, CSP, t1);
    int t2 = RH * RW * 4;
    downsample_kernel<<<(t2 + 255) / 256, 256, 0, stream>>>(im, im_r, 3, 4, t2);

    dim3 g2(RW / TILE, RH / TILE);
    bilateral_kernel<<<g2, 256, 0, stream>>>((const float4*)src_r, (const float4*)im_r, out_r);

    int t3 = IH * IW * CS;
    upsample_kernel<<<(t3 + 255) / 256, 256, 0, stream>>>(out_r, out, t3);
}

// Round 3
// 97.868 us; speedup vs baseline: 1.5421x; 1.4330x over previous
//
#include <hip/hip_runtime.h>

#define RH 128
#define RW 128
#define CS 21    // src channels
#define IH 512
#define IW 512
#define NPIX (RH * RW)
#define P 5      // dy split factor

// ---------------- K1: antialiased bilinear downsample 512 -> 128 ----------------
// planar=1: output [Cout][RH][RW]; planar=0: interleaved [RH][RW][Cout] (zero-pad c>=Cin)
template <int PLANAR>
__global__ void downsample_kernel(const float* __restrict__ in, float* __restrict__ out,
                                  int Cin, int Cout, int total) {
    int idx = blockIdx.x * blockDim.x + threadIdx.x;
    if (idx >= total) return;
    int c = idx % Cout;
    int t = idx / Cout;
    int x = t % RW, y = t / RW;
    size_t oidx = PLANAR ? ((size_t)c * NPIX + t) : (size_t)idx;
    if (c >= Cin) { out[oidx] = 0.f; return; }

    float wy[8], wx[8];
    int jy[8], jx[8];
    float sy = 4.f * y + 1.5f, sx = 4.f * x + 1.5f;
    float wys = 0.f, wxs = 0.f;
#pragma unroll
    for (int k = 0; k < 8; ++k) {
        int j = 4 * y - 2 + k;
        float w = 1.f - fabsf(sy - (float)j) * 0.25f;
        if (j < 0 || j >= IH) { w = 0.f; j = 0; }
        jy[k] = j; wy[k] = w; wys += w;
        int j2 = 4 * x - 2 + k;
        float w2 = 1.f - fabsf(sx - (float)j2) * 0.25f;
        if (j2 < 0 || j2 >= IW) { w2 = 0.f; j2 = 0; }
        jx[k] = j2; wx[k] = w2; wxs += w2;
    }
    float inv = 1.f / (wys * wxs);
    float s = 0.f;
#pragma unroll
    for (int a = 0; a < 8; ++a) {
        const float* row = in + (size_t)(jy[a] * IW) * Cin + c;
        float rs = 0.f;
#pragma unroll
        for (int b = 0; b < 8; ++b) rs += wx[b] * row[jx[b] * Cin];
        s += wy[a] * rs;
    }
    out[oidx] = s * inv;
}

// ---------------- K2: joint bilateral at 128x128, planar src ----------------
// wave = 64 consecutive x of one row y; handles dy = p, p+P, ... (P=5 split).
// All loads coalesced. OOB taps: clamped address + cw=0 (branchless).
// partials: part[p][c][pix]
__global__ __launch_bounds__(256) void bilateral_kernel(
        const float* __restrict__ srcp,   // [21][128][128] planar
        const float4* __restrict__ imr,   // [128*128] rgb+pad
        float* __restrict__ part) {       // [P][21][NPIX]
    int wid = (blockIdx.x << 2) + (threadIdx.x >> 6);   // 0..1279
    int lane = threadIdx.x & 63;
    int h = wid & 1;
    int y = (wid >> 1) & (RH - 1);
    int p = wid >> 8;                                   // 0..4
    int x = (h << 6) + lane;

    float4 ctr = imr[(y << 7) + x];
    float acc[CS];
#pragma unroll
    for (int c = 0; c < CS; ++c) acc[c] = 0.f;

    for (int dy = p; dy < 25; dy += P) {
        int ry = y + dy - 12;
        if (ry < 0 || ry >= RH) continue;               // wave-uniform
        float fdy = (float)(dy - 12);
        float gy = fdy * fdy;
        const float* srow = srcp + (ry << 7);           // + (c<<14) + rx
        const float4* irow = imr + (ry << 7);
#pragma unroll 5
        for (int dx = 0; dx < 25; ++dx) {
            int rx = x + dx - 12;
            bool ok = (rx >= 0) & (rx < RW);
            int rxc = min(max(rx, 0), RW - 1);
            float4 q = irow[rxc];
            float d0 = q.x - ctr.x, d1 = q.y - ctr.y, d2 = q.z - ctr.z;
            float fdx = (float)(dx - 12);
            float e = -(d0 * d0 + d1 * d1 + d2 * d2) * (1.f / 18.f)
                      - (gy + fdx * fdx) * (1.f / 128.f);
            float cw = ok ? __expf(e) : 0.f;
#pragma unroll
            for (int c = 0; c < CS; ++c)
                acc[c] = fmaf(cw, srow[(c << 14) + rxc], acc[c]);
        }
    }
    int pix = (y << 7) + x;
#pragma unroll
    for (int c = 0; c < CS; ++c)
        part[((size_t)(p * CS + c) << 14) + pix] = acc[c];
}

// ---------------- K2b: reduce partials ----------------
__global__ void reduce_kernel(const float* __restrict__ part, float* __restrict__ outr) {
    int t = blockIdx.x * blockDim.x + threadIdx.x;
    if (t >= CS * NPIX) return;
    int c = t >> 14;
    int pix = t & (NPIX - 1);
    float s = 0.f;
#pragma unroll
    for (int p = 0; p < P; ++p)
        s += part[((size_t)(p * CS + c) << 14) + pix];
    outr[(size_t)pix * CS + c] = s;
}

// ---------------- K3: bilinear upsample 128 -> 512 ----------------
__global__ void upsample_kernel(const float* __restrict__ inr, float* __restrict__ out, int total) {
    int idx = blockIdx.x * blockDim.x + threadIdx.x;
    if (idx >= total) return;
    int c = idx % CS;
    int t = idx / CS;
    int X = t % IW, Y = t / IW;
    float fy = 0.25f * (float)Y - 0.375f;
    float fx = 0.25f * (float)X - 0.375f;
    int y0 = (int)floorf(fy); float ty = fy - (float)y0;
    int x0 = (int)floorf(fx); float tx = fx - (float)x0;
    int y1 = y0 + 1, x1 = x0 + 1;
    y0 = min(max(y0, 0), RH - 1); y1 = min(max(y1, 0), RH - 1);
    x0 = min(max(x0, 0), RW - 1); x1 = min(max(x1, 0), RW - 1);
    float v00 = inr[(y0 * RW + x0) * CS + c], v01 = inr[(y0 * RW + x1) * CS + c];
    float v10 = inr[(y1 * RW + x0) * CS + c], v11 = inr[(y1 * RW + x1) * CS + c];
    float v0 = v00 + tx * (v01 - v00);
    float v1 = v10 + tx * (v11 - v10);
    out[idx] = v0 + ty * (v1 - v0);
}

extern "C" void kernel_launch(void* const* d_in, const int* in_sizes, int n_in,
                              void* d_out, int out_size, void* d_ws, size_t ws_size,
                              hipStream_t stream) {
    const float* src = (const float*)d_in[0];   // (1,512,512,21) f32
    const float* im  = (const float*)d_in[1];   // (1,512,512,3)  f32
    float* out = (float*)d_out;                 // (1,512,512,21) f32
    char* ws = (char*)d_ws;

    float* src_r = (float*)(ws);                // planar [21][128][128] = 1,376,256 B
    float* im_r  = (float*)(ws + 1376256);      // [128][128][4]        =   262,144 B
    float* out_r = (float*)(ws + 1638400);      // [128][128][21]       = 1,376,256 B
    float* part  = out;                         // scratch in d_out: [5][21][16384] = 6.9 MB (< 22 MB)

    int t1 = NPIX * CS;
    downsample_kernel<1><<<(t1 + 255) / 256, 256, 0, stream>>>(src, src_r, CS, CS, t1);
    int t2 = NPIX * 4;
    downsample_kernel<0><<<(t2 + 255) / 256, 256, 0, stream>>>(im, im_r, 3, 4, t2);

    // 1280 waves = 320 blocks of 4 waves
    bilateral_kernel<<<320, 256, 0, stream>>>(src_r, (const float4*)im_r, part);

    int tr = CS * NPIX;
    reduce_kernel<<<(tr + 255) / 256, 256, 0, stream>>>(part, out_r);

    int t3 = IH * IW * CS;
    upsample_kernel<<<(t3 + 255) / 256, 256, 0, stream>>>(out_r, out, t3);
}